// Round 1
// baseline (1416.765 us; speedup 1.0000x reference)
//
#include <hip/hip_runtime.h>

// out = segment_sum(adj_val * x[adj_src], adj_dst) @ W  +  x @ Wr
// Reordered: z = x@W ; out = x@Wr ; out[dst] += val * z[src]  (linear map commutes)

#define TILE_M 64
#define LDA_PAD 132   // 64x128 A tile padded to kill 4-way bank conflict on row reads

__global__ __launch_bounds__(256) void gemm_xw(const float* __restrict__ x,
                                               const float* __restrict__ W,
                                               const float* __restrict__ Wr,
                                               float* __restrict__ z,
                                               float* __restrict__ out,
                                               int N)
{
    __shared__ float As[TILE_M][LDA_PAD];  // 64 x 128 (padded)
    __shared__ float Bs[128][64];          // k x 64-col slice of W or Wr

    const int tid = threadIdx.x;
    const int tx = tid & 15;   // 16 col-groups (4 cols each)
    const int ty = tid >> 4;   // 16 row-groups (4 rows each)
    const int rowBase = blockIdx.x * TILE_M;
    const int cb = blockIdx.y;               // 0,1 -> W->z ; 2,3 -> Wr->out
    const float* __restrict__ Bsrc = (cb < 2) ? W : Wr;
    const int cBase = (cb & 1) * 64;

    // Load A tile: 64 rows x 128 k  (8192 floats, float4 per thread x 8)
    #pragma unroll
    for (int it = 0; it < 8; ++it) {
        int flat = (it * 256 + tid) * 4;
        int r = flat >> 7;
        int k = flat & 127;
        float4 v = make_float4(0.f, 0.f, 0.f, 0.f);
        int row = rowBase + r;
        if (row < N) v = *reinterpret_cast<const float4*>(&x[(size_t)row * 128 + k]);
        *reinterpret_cast<float4*>(&As[r][k]) = v;
    }
    // Load B tile: 128 k x 64 cols
    #pragma unroll
    for (int it = 0; it < 8; ++it) {
        int flat = (it * 256 + tid) * 4;
        int r = flat >> 6;
        int c = flat & 63;
        float4 v = *reinterpret_cast<const float4*>(&Bsrc[r * 128 + cBase + c]);
        *reinterpret_cast<float4*>(&Bs[r][c]) = v;
    }
    __syncthreads();

    float acc[4][4] = {};
    #pragma unroll 4
    for (int k0 = 0; k0 < 128; k0 += 4) {
        float4 av[4], bv[4];
        #pragma unroll
        for (int i = 0; i < 4; ++i)
            av[i] = *reinterpret_cast<const float4*>(&As[ty * 4 + i][k0]);
        #pragma unroll
        for (int kk = 0; kk < 4; ++kk)
            bv[kk] = *reinterpret_cast<const float4*>(&Bs[k0 + kk][tx * 4]);
        const float* ap = reinterpret_cast<const float*>(av);
        const float* bp = reinterpret_cast<const float*>(bv);
        #pragma unroll
        for (int kk = 0; kk < 4; ++kk)
            #pragma unroll
            for (int i = 0; i < 4; ++i)
                #pragma unroll
                for (int j = 0; j < 4; ++j)
                    acc[i][j] = fmaf(ap[i * 4 + kk], bp[kk * 4 + j], acc[i][j]);
    }

    float* __restrict__ dstbase = (cb < 2) ? z : out;
    #pragma unroll
    for (int i = 0; i < 4; ++i) {
        int row = rowBase + ty * 4 + i;
        if (row >= N) continue;
        float4 v = make_float4(acc[i][0], acc[i][1], acc[i][2], acc[i][3]);
        *reinterpret_cast<float4*>(&dstbase[(size_t)row * 128 + cBase + tx * 4]) = v;
    }
}

__global__ __launch_bounds__(256) void spmm_scatter(const float* __restrict__ z,
                                                    const float* __restrict__ val,
                                                    const int* __restrict__ src,
                                                    const int* __restrict__ dst,
                                                    float* __restrict__ out,
                                                    int E)
{
    const int lane = threadIdx.x & 63;
    const int wid = (int)((blockIdx.x * blockDim.x + threadIdx.x) >> 6);
    const int nw = (int)((gridDim.x * blockDim.x) >> 6);
    for (int e = wid; e < E; e += nw) {
        float v = val[e];
        int s = src[e];
        int d = dst[e];
        float2 zv = reinterpret_cast<const float2*>(z)[(size_t)s * 64 + lane];
        atomicAdd(&out[(size_t)d * 128 + lane * 2 + 0], v * zv.x);
        atomicAdd(&out[(size_t)d * 128 + lane * 2 + 1], v * zv.y);
    }
}

extern "C" void kernel_launch(void* const* d_in, const int* in_sizes, int n_in,
                              void* d_out, int out_size, void* d_ws, size_t ws_size,
                              hipStream_t stream) {
    const float* x    = (const float*)d_in[0];
    // d_in[1] = h0 (unused, variant=False)
    const float* aval = (const float*)d_in[2];
    const float* W    = (const float*)d_in[3];
    const float* Wr   = (const float*)d_in[4];
    const int*   asrc = (const int*)d_in[5];
    const int*   adst = (const int*)d_in[6];
    float* out = (float*)d_out;
    float* z   = (float*)d_ws;   // N*128 floats = 51.2 MB scratch

    const int N = in_sizes[0] / 128;
    const int E = in_sizes[2];

    dim3 g1((N + TILE_M - 1) / TILE_M, 4);
    gemm_xw<<<g1, 256, 0, stream>>>(x, W, Wr, z, out, N);
    spmm_scatter<<<4096, 256, 0, stream>>>(z, aval, asrc, adst, out, E);
}

// Round 2
// 463.437 us; speedup vs baseline: 3.0571x; 3.0571x over previous
//
#include <hip/hip_runtime.h>

// out = segment_sum(adj_val * x[adj_src], adj_dst) @ W  +  x @ Wr
// Reordered: z = x@W ; out = x@Wr ; then CSR-by-dst gather: out[n] += sum val*z[src]
// CSR built on device: histogram -> exclusive scan -> bin sort (no fp atomics).

#define TILE_M 64

// ---------------- GEMM: z = x@W, out = x@Wr (one A-tile load, two B passes) --
__global__ __launch_bounds__(256) void gemm_xw(const float* __restrict__ x,
                                               const float* __restrict__ W,
                                               const float* __restrict__ Wr,
                                               float* __restrict__ z,
                                               float* __restrict__ out,
                                               int N)
{
    __shared__ float As[TILE_M][132];  // padded
    __shared__ float Bs[128][64];

    const int tid = threadIdx.x;
    const int tx = tid & 15;   // 16 col-groups (4 cols each)
    const int ty = tid >> 4;   // 16 row-groups (4 rows each)
    const int rowBase = blockIdx.x * TILE_M;
    const int cBase = blockIdx.y * 64;   // column half

    // Load A tile: 64 rows x 128 k
    #pragma unroll
    for (int it = 0; it < 8; ++it) {
        int flat = (it * 256 + tid) * 4;
        int r = flat >> 7;
        int k = flat & 127;
        float4 v = make_float4(0.f, 0.f, 0.f, 0.f);
        int row = rowBase + r;
        if (row < N) v = *reinterpret_cast<const float4*>(&x[(size_t)row * 128 + k]);
        *reinterpret_cast<float4*>(&As[r][k]) = v;
    }

    float acc0[4][4] = {};
    float acc1[4][4] = {};

    #pragma unroll
    for (int pass = 0; pass < 2; ++pass) {
        const float* __restrict__ Bsrc = pass ? Wr : W;
        if (pass) __syncthreads();   // done reading Bs from pass 0
        #pragma unroll
        for (int it = 0; it < 8; ++it) {
            int flat = (it * 256 + tid) * 4;
            int r = flat >> 6;
            int c = flat & 63;
            float4 v = *reinterpret_cast<const float4*>(&Bsrc[r * 128 + cBase + c]);
            *reinterpret_cast<float4*>(&Bs[r][c]) = v;
        }
        __syncthreads();

        float (*acc)[4] = pass ? acc1 : acc0;
        #pragma unroll 4
        for (int k0 = 0; k0 < 128; k0 += 4) {
            float4 av[4], bv[4];
            #pragma unroll
            for (int i = 0; i < 4; ++i)
                av[i] = *reinterpret_cast<const float4*>(&As[ty * 4 + i][k0]);
            #pragma unroll
            for (int kk = 0; kk < 4; ++kk)
                bv[kk] = *reinterpret_cast<const float4*>(&Bs[k0 + kk][tx * 4]);
            const float* ap = reinterpret_cast<const float*>(av);
            const float* bp = reinterpret_cast<const float*>(bv);
            #pragma unroll
            for (int kk = 0; kk < 4; ++kk)
                #pragma unroll
                for (int i = 0; i < 4; ++i)
                    #pragma unroll
                    for (int j = 0; j < 4; ++j)
                        acc[i][j] = fmaf(ap[i * 4 + kk], bp[kk * 4 + j], acc[i][j]);
        }
    }

    #pragma unroll
    for (int i = 0; i < 4; ++i) {
        int row = rowBase + ty * 4 + i;
        if (row >= N) continue;
        float4 v0 = make_float4(acc0[i][0], acc0[i][1], acc0[i][2], acc0[i][3]);
        float4 v1 = make_float4(acc1[i][0], acc1[i][1], acc1[i][2], acc1[i][3]);
        *reinterpret_cast<float4*>(&z[(size_t)row * 128 + cBase + tx * 4]) = v0;
        *reinterpret_cast<float4*>(&out[(size_t)row * 128 + cBase + tx * 4]) = v1;
    }
}

// ---------------- CSR build ------------------------------------------------
__global__ __launch_bounds__(256) void zero_i(int* __restrict__ p, int n) {
    int i = blockIdx.x * 256 + threadIdx.x;
    if (i < n) p[i] = 0;
}

__global__ __launch_bounds__(256) void hist(const int* __restrict__ dst, int* __restrict__ cnt, int E) {
    int i = blockIdx.x * 256 + threadIdx.x;
    if (i < E) atomicAdd(&cnt[dst[i]], 1);
}

// block scans 512 elements (256 threads x 2), writes local-exclusive + block sum
__global__ __launch_bounds__(256) void scan1(const int* __restrict__ cnt, int* __restrict__ off,
                                             int* __restrict__ bsum, int N) {
    __shared__ int sh[256];
    const int t = threadIdx.x;
    const int i0 = blockIdx.x * 512 + t * 2;
    int c0 = (i0 < N) ? cnt[i0] : 0;
    int c1 = (i0 + 1 < N) ? cnt[i0 + 1] : 0;
    int s = c0 + c1;
    sh[t] = s;
    __syncthreads();
    #pragma unroll
    for (int d = 1; d < 256; d <<= 1) {
        int v = (t >= d) ? sh[t - d] : 0;
        __syncthreads();
        sh[t] += v;
        __syncthreads();
    }
    int ex = sh[t] - s;
    if (i0 < N) off[i0] = ex;
    if (i0 + 1 < N) off[i0 + 1] = ex + c0;
    if (t == 255) bsum[blockIdx.x] = sh[255];
}

// single-block exclusive scan of block sums (nB <= 256)
__global__ __launch_bounds__(256) void scan2(int* __restrict__ bsum, int nB) {
    __shared__ int sh[256];
    const int t = threadIdx.x;
    int v0 = (t < nB) ? bsum[t] : 0;
    sh[t] = v0;
    __syncthreads();
    #pragma unroll
    for (int d = 1; d < 256; d <<= 1) {
        int v = (t >= d) ? sh[t - d] : 0;
        __syncthreads();
        sh[t] += v;
        __syncthreads();
    }
    int ex = sh[t] - v0;
    if (t < nB) bsum[t] = ex;
}

__global__ __launch_bounds__(256) void scan3(int* __restrict__ off, const int* __restrict__ bsum,
                                             int* __restrict__ cursor, int N) {
    int i = blockIdx.x * 256 + threadIdx.x;
    if (i < N) {
        int o = off[i] + bsum[i >> 9];
        off[i] = o;
        cursor[i] = o;
    }
}

__global__ __launch_bounds__(256) void binsort(const float* __restrict__ val, const int* __restrict__ src,
                                               const int* __restrict__ dst, int* __restrict__ cursor,
                                               float* __restrict__ sval, int* __restrict__ ssrc, int E) {
    int e = blockIdx.x * 256 + threadIdx.x;
    if (e < E) {
        int d = dst[e];
        int p = atomicAdd(&cursor[d], 1);
        sval[p] = val[e];
        ssrc[p] = src[e];
    }
}

// ---------------- gather-side accumulation: one wave per node ---------------
__global__ __launch_bounds__(256) void spmm_gather(const float* __restrict__ z,
                                                   const float* __restrict__ sval,
                                                   const int* __restrict__ ssrc,
                                                   const int* __restrict__ off,
                                                   const int* __restrict__ cnt,
                                                   float* out, int N) {
    const int lane = threadIdx.x & 63;
    const int node = (int)((blockIdx.x * (size_t)blockDim.x + threadIdx.x) >> 6);
    if (node >= N) return;
    const int base = off[node];
    const int end = base + cnt[node];
    float2 acc = reinterpret_cast<const float2*>(out)[(size_t)node * 64 + lane];
    for (int e = base; e < end; ++e) {
        float v = sval[e];
        int s = ssrc[e];
        float2 zv = reinterpret_cast<const float2*>(z)[(size_t)s * 64 + lane];
        acc.x = fmaf(v, zv.x, acc.x);
        acc.y = fmaf(v, zv.y, acc.y);
    }
    reinterpret_cast<float2*>(out)[(size_t)node * 64 + lane] = acc;
}

// ---------------- fallback (old atomic scatter) -----------------------------
__global__ __launch_bounds__(256) void spmm_scatter(const float* __restrict__ z,
                                                    const float* __restrict__ val,
                                                    const int* __restrict__ src,
                                                    const int* __restrict__ dst,
                                                    float* __restrict__ out,
                                                    int E) {
    const int lane = threadIdx.x & 63;
    const int wid = (int)((blockIdx.x * blockDim.x + threadIdx.x) >> 6);
    const int nw = (int)((gridDim.x * blockDim.x) >> 6);
    for (int e = wid; e < E; e += nw) {
        float v = val[e];
        int s = src[e];
        int d = dst[e];
        float2 zv = reinterpret_cast<const float2*>(z)[(size_t)s * 64 + lane];
        atomicAdd(&out[(size_t)d * 128 + lane * 2 + 0], v * zv.x);
        atomicAdd(&out[(size_t)d * 128 + lane * 2 + 1], v * zv.y);
    }
}

extern "C" void kernel_launch(void* const* d_in, const int* in_sizes, int n_in,
                              void* d_out, int out_size, void* d_ws, size_t ws_size,
                              hipStream_t stream) {
    const float* x    = (const float*)d_in[0];
    // d_in[1] = h0 (unused, variant=False)
    const float* aval = (const float*)d_in[2];
    const float* W    = (const float*)d_in[3];
    const float* Wr   = (const float*)d_in[4];
    const int*   asrc = (const int*)d_in[5];
    const int*   adst = (const int*)d_in[6];
    float* out = (float*)d_out;

    const int N = in_sizes[0] / 128;
    const int E = in_sizes[2];
    const int nB = (N + 511) / 512;

    // workspace layout
    char* w = (char*)d_ws;
    float* z = (float*)w;          w += (size_t)N * 128 * 4;
    int* cnt = (int*)w;            w += (size_t)N * 4;
    int* off = (int*)w;            w += (size_t)N * 4;
    int* cursor = (int*)w;         w += (size_t)N * 4;
    int* bsum = (int*)w;           w += 4096;
    float* sval = (float*)w;       w += (size_t)E * 4;
    int* ssrc = (int*)w;           w += (size_t)E * 4;
    size_t need = (size_t)(w - (char*)d_ws);

    dim3 g1((N + TILE_M - 1) / TILE_M, 2);
    gemm_xw<<<g1, 256, 0, stream>>>(x, W, Wr, z, out, N);

    if (need <= ws_size && nB <= 256) {
        zero_i<<<(N + 255) / 256, 256, 0, stream>>>(cnt, N);
        hist<<<(E + 255) / 256, 256, 0, stream>>>(adst, cnt, E);
        scan1<<<nB, 256, 0, stream>>>(cnt, off, bsum, N);
        scan2<<<1, 256, 0, stream>>>(bsum, nB);
        scan3<<<(N + 255) / 256, 256, 0, stream>>>(off, bsum, cursor, N);
        binsort<<<(E + 255) / 256, 256, 0, stream>>>(aval, asrc, adst, cursor, sval, ssrc, E);
        spmm_gather<<<(int)(((size_t)N * 64 + 255) / 256), 256, 0, stream>>>(z, sval, ssrc, off, cnt, out, N);
    } else {
        spmm_scatter<<<4096, 256, 0, stream>>>(z, aval, asrc, adst, out, E);
    }
}

// Round 3
// 413.217 us; speedup vs baseline: 3.4286x; 1.1215x over previous
//
#include <hip/hip_runtime.h>

// out = segment_sum(adj_val * x[adj_src], adj_dst) @ W  +  x @ Wr
// Reordered: z = x@W ; out = x@Wr ; then CSR-by-dst gather: out[n] += sum val*z[src]
// CSR built on device: histogram -> exclusive scan -> bin sort (packed 8B payload).

#define TILE_M 64

// ---------------- GEMM: z = x@W, out = x@Wr (one A-tile load, two B passes) --
__global__ __launch_bounds__(256) void gemm_xw(const float* __restrict__ x,
                                               const float* __restrict__ W,
                                               const float* __restrict__ Wr,
                                               float* __restrict__ z,
                                               float* __restrict__ out,
                                               int N)
{
    __shared__ float As[TILE_M][132];  // padded
    __shared__ float Bs[128][64];

    const int tid = threadIdx.x;
    const int tx = tid & 15;   // 16 col-groups (4 cols each)
    const int ty = tid >> 4;   // 16 row-groups (4 rows each)
    const int rowBase = blockIdx.x * TILE_M;
    const int cBase = blockIdx.y * 64;   // column half

    #pragma unroll
    for (int it = 0; it < 8; ++it) {
        int flat = (it * 256 + tid) * 4;
        int r = flat >> 7;
        int k = flat & 127;
        float4 v = make_float4(0.f, 0.f, 0.f, 0.f);
        int row = rowBase + r;
        if (row < N) v = *reinterpret_cast<const float4*>(&x[(size_t)row * 128 + k]);
        *reinterpret_cast<float4*>(&As[r][k]) = v;
    }

    float acc0[4][4] = {};
    float acc1[4][4] = {};

    #pragma unroll
    for (int pass = 0; pass < 2; ++pass) {
        const float* __restrict__ Bsrc = pass ? Wr : W;
        if (pass) __syncthreads();   // done reading Bs from pass 0
        #pragma unroll
        for (int it = 0; it < 8; ++it) {
            int flat = (it * 256 + tid) * 4;
            int r = flat >> 6;
            int c = flat & 63;
            float4 v = *reinterpret_cast<const float4*>(&Bsrc[r * 128 + cBase + c]);
            *reinterpret_cast<float4*>(&Bs[r][c]) = v;
        }
        __syncthreads();

        float (*acc)[4] = pass ? acc1 : acc0;
        #pragma unroll 4
        for (int k0 = 0; k0 < 128; k0 += 4) {
            float4 av[4], bv[4];
            #pragma unroll
            for (int i = 0; i < 4; ++i)
                av[i] = *reinterpret_cast<const float4*>(&As[ty * 4 + i][k0]);
            #pragma unroll
            for (int kk = 0; kk < 4; ++kk)
                bv[kk] = *reinterpret_cast<const float4*>(&Bs[k0 + kk][tx * 4]);
            const float* ap = reinterpret_cast<const float*>(av);
            const float* bp = reinterpret_cast<const float*>(bv);
            #pragma unroll
            for (int kk = 0; kk < 4; ++kk)
                #pragma unroll
                for (int i = 0; i < 4; ++i)
                    #pragma unroll
                    for (int j = 0; j < 4; ++j)
                        acc[i][j] = fmaf(ap[i * 4 + kk], bp[kk * 4 + j], acc[i][j]);
        }
    }

    #pragma unroll
    for (int i = 0; i < 4; ++i) {
        int row = rowBase + ty * 4 + i;
        if (row >= N) continue;
        float4 v0 = make_float4(acc0[i][0], acc0[i][1], acc0[i][2], acc0[i][3]);
        float4 v1 = make_float4(acc1[i][0], acc1[i][1], acc1[i][2], acc1[i][3]);
        *reinterpret_cast<float4*>(&z[(size_t)row * 128 + cBase + tx * 4]) = v0;
        *reinterpret_cast<float4*>(&out[(size_t)row * 128 + cBase + tx * 4]) = v1;
    }
}

// ---------------- CSR build ------------------------------------------------
__global__ __launch_bounds__(256) void zero_i(int* __restrict__ p, int n) {
    int i = blockIdx.x * 256 + threadIdx.x;
    if (i < n) p[i] = 0;
}

__global__ __launch_bounds__(256) void hist(const int* __restrict__ dst, int* __restrict__ cnt, int E) {
    int i = blockIdx.x * 256 + threadIdx.x;
    if (i < E) atomicAdd(&cnt[dst[i]], 1);
}

__global__ __launch_bounds__(256) void scan1(const int* __restrict__ cnt, int* __restrict__ off,
                                             int* __restrict__ bsum, int N) {
    __shared__ int sh[256];
    const int t = threadIdx.x;
    const int i0 = blockIdx.x * 512 + t * 2;
    int c0 = (i0 < N) ? cnt[i0] : 0;
    int c1 = (i0 + 1 < N) ? cnt[i0 + 1] : 0;
    int s = c0 + c1;
    sh[t] = s;
    __syncthreads();
    #pragma unroll
    for (int d = 1; d < 256; d <<= 1) {
        int v = (t >= d) ? sh[t - d] : 0;
        __syncthreads();
        sh[t] += v;
        __syncthreads();
    }
    int ex = sh[t] - s;
    if (i0 < N) off[i0] = ex;
    if (i0 + 1 < N) off[i0 + 1] = ex + c0;
    if (t == 255) bsum[blockIdx.x] = sh[255];
}

__global__ __launch_bounds__(256) void scan2(int* __restrict__ bsum, int nB) {
    __shared__ int sh[256];
    const int t = threadIdx.x;
    int v0 = (t < nB) ? bsum[t] : 0;
    sh[t] = v0;
    __syncthreads();
    #pragma unroll
    for (int d = 1; d < 256; d <<= 1) {
        int v = (t >= d) ? sh[t - d] : 0;
        __syncthreads();
        sh[t] += v;
        __syncthreads();
    }
    int ex = sh[t] - v0;
    if (t < nB) bsum[t] = ex;
}

__global__ __launch_bounds__(256) void scan3(int* __restrict__ off, const int* __restrict__ bsum,
                                             int* __restrict__ cursor, int N) {
    int i = blockIdx.x * 256 + threadIdx.x;
    if (i < N) {
        int o = off[i] + bsum[i >> 9];
        off[i] = o;
        cursor[i] = o;
    }
}

// packed (src, val) single 8B random write per edge
__global__ __launch_bounds__(256) void binsort(const float* __restrict__ val, const int* __restrict__ src,
                                               const int* __restrict__ dst, int* __restrict__ cursor,
                                               uint2* __restrict__ epk, int E) {
    int e = blockIdx.x * 256 + threadIdx.x;
    if (e < E) {
        int d = dst[e];
        int p = atomicAdd(&cursor[d], 1);
        epk[p] = make_uint2((unsigned)src[e], __float_as_uint(val[e]));
    }
}

// ---------------- gather: one wave per node, 4-deep edge pipeline ----------
__global__ __launch_bounds__(256) void spmm_gather(const float* __restrict__ z,
                                                   const uint2* __restrict__ epk,
                                                   const int* __restrict__ off,
                                                   const int* __restrict__ cnt,
                                                   float* __restrict__ out, int N) {
    const int lane = threadIdx.x & 63;
    const int node = (int)((blockIdx.x * (size_t)blockDim.x + threadIdx.x) >> 6);
    if (node >= N) return;
    const int base = off[node];
    const int end = base + cnt[node];
    const float2* __restrict__ zz = reinterpret_cast<const float2*>(z);
    float2 acc = reinterpret_cast<const float2*>(out)[(size_t)node * 64 + lane];
    int e = base;
    for (; e + 4 <= end; e += 4) {
        uint2 p0 = epk[e + 0];
        uint2 p1 = epk[e + 1];
        uint2 p2 = epk[e + 2];
        uint2 p3 = epk[e + 3];
        float2 z0 = zz[(size_t)p0.x * 64 + lane];
        float2 z1 = zz[(size_t)p1.x * 64 + lane];
        float2 z2 = zz[(size_t)p2.x * 64 + lane];
        float2 z3 = zz[(size_t)p3.x * 64 + lane];
        float v0 = __uint_as_float(p0.y), v1 = __uint_as_float(p1.y);
        float v2 = __uint_as_float(p2.y), v3 = __uint_as_float(p3.y);
        acc.x = fmaf(v0, z0.x, acc.x); acc.y = fmaf(v0, z0.y, acc.y);
        acc.x = fmaf(v1, z1.x, acc.x); acc.y = fmaf(v1, z1.y, acc.y);
        acc.x = fmaf(v2, z2.x, acc.x); acc.y = fmaf(v2, z2.y, acc.y);
        acc.x = fmaf(v3, z3.x, acc.x); acc.y = fmaf(v3, z3.y, acc.y);
    }
    for (; e < end; ++e) {
        uint2 p = epk[e];
        float2 zv = zz[(size_t)p.x * 64 + lane];
        float v = __uint_as_float(p.y);
        acc.x = fmaf(v, zv.x, acc.x);
        acc.y = fmaf(v, zv.y, acc.y);
    }
    reinterpret_cast<float2*>(out)[(size_t)node * 64 + lane] = acc;
}

// ---------------- fallback (atomic scatter) --------------------------------
__global__ __launch_bounds__(256) void spmm_scatter(const float* __restrict__ z,
                                                    const float* __restrict__ val,
                                                    const int* __restrict__ src,
                                                    const int* __restrict__ dst,
                                                    float* __restrict__ out,
                                                    int E) {
    const int lane = threadIdx.x & 63;
    const int wid = (int)((blockIdx.x * blockDim.x + threadIdx.x) >> 6);
    const int nw = (int)((gridDim.x * blockDim.x) >> 6);
    for (int e = wid; e < E; e += nw) {
        float v = val[e];
        int s = src[e];
        int d = dst[e];
        float2 zv = reinterpret_cast<const float2*>(z)[(size_t)s * 64 + lane];
        atomicAdd(&out[(size_t)d * 128 + lane * 2 + 0], v * zv.x);
        atomicAdd(&out[(size_t)d * 128 + lane * 2 + 1], v * zv.y);
    }
}

extern "C" void kernel_launch(void* const* d_in, const int* in_sizes, int n_in,
                              void* d_out, int out_size, void* d_ws, size_t ws_size,
                              hipStream_t stream) {
    const float* x    = (const float*)d_in[0];
    // d_in[1] = h0 (unused, variant=False)
    const float* aval = (const float*)d_in[2];
    const float* W    = (const float*)d_in[3];
    const float* Wr   = (const float*)d_in[4];
    const int*   asrc = (const int*)d_in[5];
    const int*   adst = (const int*)d_in[6];
    float* out = (float*)d_out;

    const int N = in_sizes[0] / 128;
    const int E = in_sizes[2];
    const int nB = (N + 511) / 512;

    // workspace layout (all offsets stay 8B-aligned for uint2)
    char* w = (char*)d_ws;
    float* z = (float*)w;          w += (size_t)N * 128 * 4;
    int* cnt = (int*)w;            w += (size_t)N * 4;
    int* off = (int*)w;            w += (size_t)N * 4;
    int* cursor = (int*)w;         w += (size_t)N * 4;
    int* bsum = (int*)w;           w += 4096;
    uint2* epk = (uint2*)w;        w += (size_t)E * 8;
    size_t need = (size_t)(w - (char*)d_ws);

    dim3 g1((N + TILE_M - 1) / TILE_M, 2);
    gemm_xw<<<g1, 256, 0, stream>>>(x, W, Wr, z, out, N);

    if (need <= ws_size && nB <= 256) {
        zero_i<<<(N + 255) / 256, 256, 0, stream>>>(cnt, N);
        hist<<<(E + 255) / 256, 256, 0, stream>>>(adst, cnt, E);
        scan1<<<nB, 256, 0, stream>>>(cnt, off, bsum, N);
        scan2<<<1, 256, 0, stream>>>(bsum, nB);
        scan3<<<(N + 255) / 256, 256, 0, stream>>>(off, bsum, cursor, N);
        binsort<<<(E + 255) / 256, 256, 0, stream>>>(aval, asrc, adst, cursor, epk, E);
        spmm_gather<<<(int)(((size_t)N * 64 + 255) / 256), 256, 0, stream>>>(z, epk, off, cnt, out, N);
    } else {
        spmm_scatter<<<4096, 256, 0, stream>>>(z, aval, asrc, adst, out, E);
    }
}

// Round 4
// 351.580 us; speedup vs baseline: 4.0297x; 1.1753x over previous
//
#include <hip/hip_runtime.h>
#include <hip/hip_fp16.h>

// out = segment_sum(adj_val * x[adj_src], adj_dst) @ W  +  x @ Wr
// Reordered: z = x@W (bf16 MFMA) ; out = x@Wr ; CSR-by-dst gather on bf16 z.

typedef __attribute__((ext_vector_type(8))) short bf16x8;
typedef __attribute__((ext_vector_type(4))) float f32x4;

__device__ __forceinline__ unsigned short f2b(float f) {   // f32 -> bf16 RNE
    unsigned u = __float_as_uint(f);
    return (unsigned short)((u + 0x7FFFu + ((u >> 16) & 1u)) >> 16);
}

// ---- convert: xb=bf16(x); Wt/Wrt = bf16(W^T/Wr^T); zero cnt --------------
__global__ __launch_bounds__(256) void convert_k(const float* __restrict__ x,
                                                 const float* __restrict__ W,
                                                 const float* __restrict__ Wr,
                                                 unsigned short* __restrict__ xb,
                                                 unsigned short* __restrict__ Wt,
                                                 unsigned short* __restrict__ Wrt,
                                                 int* __restrict__ cnt,
                                                 int nx, int N) {
    int gid = blockIdx.x * 256 + threadIdx.x;
    int i0 = gid * 8;
    if (i0 + 8 <= nx) {
        float4 a = *reinterpret_cast<const float4*>(&x[i0]);
        float4 b = *reinterpret_cast<const float4*>(&x[i0 + 4]);
        uint4 o;
        o.x = (unsigned)f2b(a.x) | ((unsigned)f2b(a.y) << 16);
        o.y = (unsigned)f2b(a.z) | ((unsigned)f2b(a.w) << 16);
        o.z = (unsigned)f2b(b.x) | ((unsigned)f2b(b.y) << 16);
        o.w = (unsigned)f2b(b.z) | ((unsigned)f2b(b.w) << 16);
        *reinterpret_cast<uint4*>(&xb[i0]) = o;
    }
    if (gid < 16384) {                 // 128x128 weight transpose
        int k = gid >> 7, n = gid & 127;
        Wt[(n << 7) + k]  = f2b(W[gid]);
        Wrt[(n << 7) + k] = f2b(Wr[gid]);
    }
    if (gid < N) cnt[gid] = 0;
}

// ---- MFMA GEMM, no LDS: z(bf16) = x@W ; out(f32) = x@Wr -------------------
// Swapped operands: A-frag = Wt rows (out-cols), B-frag = x rows. D layout
// (col=lane&15 -> x-row, row=(lane>>4)*4+reg -> 4 consecutive out-cols).
__global__ __launch_bounds__(512) void gemm_mfma(const unsigned short* __restrict__ xb,
                                                 const unsigned short* __restrict__ Wt,
                                                 const unsigned short* __restrict__ Wrt,
                                                 unsigned short* __restrict__ z,
                                                 float* __restrict__ out, int N) {
    const int tid = threadIdx.x;
    const int wave = tid >> 6;
    const int lane = tid & 63;
    const int l15 = lane & 15;
    const int lhi = lane >> 4;
    const int row = blockIdx.x * 128 + wave * 16 + l15;      // this lane's x-row
    const size_t xoff = (size_t)(row < N ? row : N - 1) * 128;

    f32x4 accW[8], accR[8];
    #pragma unroll
    for (int fn = 0; fn < 8; ++fn) { accW[fn] = (f32x4)0.f; accR[fn] = (f32x4)0.f; }

    #pragma unroll
    for (int ks = 0; ks < 4; ++ks) {
        const int kb = ks * 32 + lhi * 8;
        bf16x8 xf = *reinterpret_cast<const bf16x8*>(&xb[xoff + kb]);
        #pragma unroll
        for (int fn = 0; fn < 8; ++fn) {
            bf16x8 wf  = *reinterpret_cast<const bf16x8*>(&Wt [((fn * 16 + l15) << 7) + kb]);
            bf16x8 wrf = *reinterpret_cast<const bf16x8*>(&Wrt[((fn * 16 + l15) << 7) + kb]);
            accW[fn] = __builtin_amdgcn_mfma_f32_16x16x32_bf16(wf,  xf, accW[fn], 0, 0, 0);
            accR[fn] = __builtin_amdgcn_mfma_f32_16x16x32_bf16(wrf, xf, accR[fn], 0, 0, 0);
        }
    }

    if (row < N) {
        #pragma unroll
        for (int fn = 0; fn < 8; ++fn) {
            int c = fn * 16 + lhi * 4;
            *reinterpret_cast<f32x4*>(&out[(size_t)row * 128 + c]) = accR[fn];
            uint2 pz;
            pz.x = (unsigned)f2b(accW[fn][0]) | ((unsigned)f2b(accW[fn][1]) << 16);
            pz.y = (unsigned)f2b(accW[fn][2]) | ((unsigned)f2b(accW[fn][3]) << 16);
            *reinterpret_cast<uint2*>(&z[(size_t)row * 128 + c]) = pz;
        }
    }
}

// ---- CSR build ------------------------------------------------------------
__global__ __launch_bounds__(256) void hist(const int* __restrict__ dst, int* __restrict__ cnt, int E) {
    int i = blockIdx.x * 256 + threadIdx.x;
    if (i < E) atomicAdd(&cnt[dst[i]], 1);
}

__global__ __launch_bounds__(256) void scan1(const int* __restrict__ cnt, int* __restrict__ off,
                                             int* __restrict__ bsum, int N) {
    __shared__ int sh[256];
    const int t = threadIdx.x;
    const int i0 = blockIdx.x * 512 + t * 2;
    int c0 = (i0 < N) ? cnt[i0] : 0;
    int c1 = (i0 + 1 < N) ? cnt[i0 + 1] : 0;
    int s = c0 + c1;
    sh[t] = s;
    __syncthreads();
    #pragma unroll
    for (int d = 1; d < 256; d <<= 1) {
        int v = (t >= d) ? sh[t - d] : 0;
        __syncthreads();
        sh[t] += v;
        __syncthreads();
    }
    int ex = sh[t] - s;
    if (i0 < N) off[i0] = ex;
    if (i0 + 1 < N) off[i0 + 1] = ex + c0;
    if (t == 255) bsum[blockIdx.x] = sh[255];
}

__global__ __launch_bounds__(256) void scan2(int* __restrict__ bsum, int nB) {
    __shared__ int sh[256];
    const int t = threadIdx.x;
    int v0 = (t < nB) ? bsum[t] : 0;
    sh[t] = v0;
    __syncthreads();
    #pragma unroll
    for (int d = 1; d < 256; d <<= 1) {
        int v = (t >= d) ? sh[t - d] : 0;
        __syncthreads();
        sh[t] += v;
        __syncthreads();
    }
    int ex = sh[t] - v0;
    if (t < nB) bsum[t] = ex;
}

__global__ __launch_bounds__(256) void scan3(int* __restrict__ off, const int* __restrict__ bsum,
                                             int* __restrict__ cursor, int N) {
    int i = blockIdx.x * 256 + threadIdx.x;
    if (i < N) {
        int o = off[i] + bsum[i >> 9];
        off[i] = o;
        cursor[i] = o;
    }
}

// packed payload: src(17b) | positive-fp16 val(15b)  -> one 4B random write
__global__ __launch_bounds__(256) void binsort(const float* __restrict__ val, const int* __restrict__ src,
                                               const int* __restrict__ dst, int* __restrict__ cursor,
                                               unsigned* __restrict__ epk, int E) {
    int e = blockIdx.x * 256 + threadIdx.x;
    if (e < E) {
        int d = dst[e];
        int p = atomicAdd(&cursor[d], 1);
        __half hv = __float2half(val[e]);
        unsigned short hu;
        __builtin_memcpy(&hu, &hv, 2);
        epk[p] = ((unsigned)src[e] << 15) | (unsigned)(hu & 0x7FFFu);
    }
}

__device__ __forceinline__ float h15f(unsigned h) {
    unsigned short u = (unsigned short)(h & 0x7FFFu);
    __half hv;
    __builtin_memcpy(&hv, &u, 2);
    return __half2float(hv);
}

// ---- gather: one wave per node; epk broadcast via shfl; bf16 z ------------
__global__ __launch_bounds__(256) void spmm_gather(const unsigned* __restrict__ zz,
                                                   const unsigned* __restrict__ epk,
                                                   const int* __restrict__ off,
                                                   const int* __restrict__ cnt,
                                                   float* __restrict__ out, int N) {
    const int lane = threadIdx.x & 63;
    const int node = (int)((blockIdx.x * (size_t)blockDim.x + threadIdx.x) >> 6);
    if (node >= N) return;
    const int base = off[node];
    const int deg = cnt[node];
    float2 acc = *reinterpret_cast<const float2*>(&out[(size_t)node * 128 + lane * 2]);

    for (int b = 0; b < deg; b += 64) {
        int m = min(64, deg - b);
        unsigned pv = (lane < m) ? epk[base + b + lane] : 0u;
        int j = 0;
        for (; j + 4 <= m; j += 4) {
            unsigned p0 = __shfl(pv, j + 0);
            unsigned p1 = __shfl(pv, j + 1);
            unsigned p2 = __shfl(pv, j + 2);
            unsigned p3 = __shfl(pv, j + 3);
            unsigned z0 = zz[(size_t)(p0 >> 15) * 64 + lane];
            unsigned z1 = zz[(size_t)(p1 >> 15) * 64 + lane];
            unsigned z2 = zz[(size_t)(p2 >> 15) * 64 + lane];
            unsigned z3 = zz[(size_t)(p3 >> 15) * 64 + lane];
            float v0 = h15f(p0), v1 = h15f(p1), v2 = h15f(p2), v3 = h15f(p3);
            acc.x = fmaf(v0, __uint_as_float(z0 << 16), acc.x);
            acc.y = fmaf(v0, __uint_as_float(z0 & 0xFFFF0000u), acc.y);
            acc.x = fmaf(v1, __uint_as_float(z1 << 16), acc.x);
            acc.y = fmaf(v1, __uint_as_float(z1 & 0xFFFF0000u), acc.y);
            acc.x = fmaf(v2, __uint_as_float(z2 << 16), acc.x);
            acc.y = fmaf(v2, __uint_as_float(z2 & 0xFFFF0000u), acc.y);
            acc.x = fmaf(v3, __uint_as_float(z3 << 16), acc.x);
            acc.y = fmaf(v3, __uint_as_float(z3 & 0xFFFF0000u), acc.y);
        }
        for (; j < m; ++j) {
            unsigned p = __shfl(pv, j);
            unsigned zv = zz[(size_t)(p >> 15) * 64 + lane];
            float v = h15f(p);
            acc.x = fmaf(v, __uint_as_float(zv << 16), acc.x);
            acc.y = fmaf(v, __uint_as_float(zv & 0xFFFF0000u), acc.y);
        }
    }
    *reinterpret_cast<float2*>(&out[(size_t)node * 128 + lane * 2]) = acc;
}

extern "C" void kernel_launch(void* const* d_in, const int* in_sizes, int n_in,
                              void* d_out, int out_size, void* d_ws, size_t ws_size,
                              hipStream_t stream) {
    const float* x    = (const float*)d_in[0];
    // d_in[1] = h0 (unused, variant=False)
    const float* aval = (const float*)d_in[2];
    const float* W    = (const float*)d_in[3];
    const float* Wr   = (const float*)d_in[4];
    const int*   asrc = (const int*)d_in[5];
    const int*   adst = (const int*)d_in[6];
    float* out = (float*)d_out;

    const int nx = in_sizes[0];
    const int N = nx / 128;
    const int E = in_sizes[2];
    const int nB = (N + 511) / 512;

    // workspace layout (16B-aligned pieces)
    char* w = (char*)d_ws;
    unsigned short* xb = (unsigned short*)w;  w += (size_t)nx * 2;          // 25.6 MB
    unsigned short* z  = (unsigned short*)w;  w += (size_t)nx * 2;          // 25.6 MB
    unsigned short* Wt = (unsigned short*)w;  w += 16384 * 2;
    unsigned short* Wrt= (unsigned short*)w;  w += 16384 * 2;
    int* cnt    = (int*)w;  w += (size_t)N * 4;
    int* off    = (int*)w;  w += (size_t)N * 4;
    int* cursor = (int*)w;  w += (size_t)N * 4;
    int* bsum   = (int*)w;  w += 4096;
    unsigned* epk = (unsigned*)w;  w += (size_t)E * 4;                      // 6.4 MB

    convert_k<<<(nx / 8 + 255) / 256, 256, 0, stream>>>(x, W, Wr, xb, Wt, Wrt, cnt, nx, N);
    gemm_mfma<<<(N + 127) / 128, 512, 0, stream>>>(xb, Wt, Wrt, z, out, N);
    hist<<<(E + 255) / 256, 256, 0, stream>>>(adst, cnt, E);
    scan1<<<nB, 256, 0, stream>>>(cnt, off, bsum, N);
    scan2<<<1, 256, 0, stream>>>(bsum, nB);
    scan3<<<(N + 255) / 256, 256, 0, stream>>>(off, bsum, cursor, N);
    binsort<<<(E + 255) / 256, 256, 0, stream>>>(aval, asrc, adst, cursor, epk, E);
    spmm_gather<<<(int)(((size_t)N * 64 + 255) / 256), 256, 0, stream>>>((const unsigned*)z, epk, off, cnt, out, N);
}

// Round 5
// 299.139 us; speedup vs baseline: 4.7361x; 1.1753x over previous
//
#include <hip/hip_runtime.h>
#include <hip/hip_fp16.h>

// out = segment_sum(adj_val * x[adj_src], adj_dst) @ W  +  x @ Wr
// z = x@W (bf16 MFMA); out = x@Wr; CSR-by-dst gather on bf16 z.
// CSR built via 2-pass bin sort (coarse dst>>8, then fine) to keep the
// random-write working set L2-resident (r4: 1-pass sort caused 105MB of
// partial-line write-backs).

typedef __attribute__((ext_vector_type(8))) short bf16x8;
typedef __attribute__((ext_vector_type(4))) float f32x4;

#define BSH 8          // coarse bucket = dst >> 8  (256 nodes per bucket)
#define CHUNK 4096     // edges per block in hist/binsort1

__device__ __forceinline__ unsigned short f2b(float f) {   // f32 -> bf16 RNE
    unsigned u = __float_as_uint(f);
    return (unsigned short)((u + 0x7FFFu + ((u >> 16) & 1u)) >> 16);
}

// ---- convert: xb=bf16(x); Wt/Wrt = bf16(W^T/Wr^T); zero cnt & ccnt --------
__global__ __launch_bounds__(256) void convert_k(const float* __restrict__ x,
                                                 const float* __restrict__ W,
                                                 const float* __restrict__ Wr,
                                                 unsigned short* __restrict__ xb,
                                                 unsigned short* __restrict__ Wt,
                                                 unsigned short* __restrict__ Wrt,
                                                 int* __restrict__ cnt,
                                                 int* __restrict__ ccnt,
                                                 int nx, int N, int NBK) {
    int gid = blockIdx.x * 256 + threadIdx.x;
    int i0 = gid * 8;
    if (i0 + 8 <= nx) {
        float4 a = *reinterpret_cast<const float4*>(&x[i0]);
        float4 b = *reinterpret_cast<const float4*>(&x[i0 + 4]);
        uint4 o;
        o.x = (unsigned)f2b(a.x) | ((unsigned)f2b(a.y) << 16);
        o.y = (unsigned)f2b(a.z) | ((unsigned)f2b(a.w) << 16);
        o.z = (unsigned)f2b(b.x) | ((unsigned)f2b(b.y) << 16);
        o.w = (unsigned)f2b(b.z) | ((unsigned)f2b(b.w) << 16);
        *reinterpret_cast<uint4*>(&xb[i0]) = o;
    }
    if (gid < 16384) {                 // 128x128 weight transpose
        int k = gid >> 7, n = gid & 127;
        Wt[(n << 7) + k]  = f2b(W[gid]);
        Wrt[(n << 7) + k] = f2b(Wr[gid]);
    }
    if (gid < N) cnt[gid] = 0;
    if (gid < NBK) ccnt[gid] = 0;
}

// ---- MFMA GEMM, no LDS: z(bf16) = x@W ; out(f32) = x@Wr -------------------
__global__ __launch_bounds__(512) void gemm_mfma(const unsigned short* __restrict__ xb,
                                                 const unsigned short* __restrict__ Wt,
                                                 const unsigned short* __restrict__ Wrt,
                                                 unsigned short* __restrict__ z,
                                                 float* __restrict__ out, int N) {
    const int tid = threadIdx.x;
    const int wave = tid >> 6;
    const int lane = tid & 63;
    const int l15 = lane & 15;
    const int lhi = lane >> 4;
    const int row = blockIdx.x * 128 + wave * 16 + l15;      // this lane's x-row
    const size_t xoff = (size_t)(row < N ? row : N - 1) * 128;

    f32x4 accW[8], accR[8];
    #pragma unroll
    for (int fn = 0; fn < 8; ++fn) { accW[fn] = (f32x4)0.f; accR[fn] = (f32x4)0.f; }

    #pragma unroll
    for (int ks = 0; ks < 4; ++ks) {
        const int kb = ks * 32 + lhi * 8;
        bf16x8 xf = *reinterpret_cast<const bf16x8*>(&xb[xoff + kb]);
        #pragma unroll
        for (int fn = 0; fn < 8; ++fn) {
            bf16x8 wf  = *reinterpret_cast<const bf16x8*>(&Wt [((fn * 16 + l15) << 7) + kb]);
            bf16x8 wrf = *reinterpret_cast<const bf16x8*>(&Wrt[((fn * 16 + l15) << 7) + kb]);
            accW[fn] = __builtin_amdgcn_mfma_f32_16x16x32_bf16(wf,  xf, accW[fn], 0, 0, 0);
            accR[fn] = __builtin_amdgcn_mfma_f32_16x16x32_bf16(wrf, xf, accR[fn], 0, 0, 0);
        }
    }

    if (row < N) {
        #pragma unroll
        for (int fn = 0; fn < 8; ++fn) {
            int c = fn * 16 + lhi * 4;
            *reinterpret_cast<f32x4*>(&out[(size_t)row * 128 + c]) = accR[fn];
            uint2 pz;
            pz.x = (unsigned)f2b(accW[fn][0]) | ((unsigned)f2b(accW[fn][1]) << 16);
            pz.y = (unsigned)f2b(accW[fn][2]) | ((unsigned)f2b(accW[fn][3]) << 16);
            *reinterpret_cast<uint2*>(&z[(size_t)row * 128 + c]) = pz;
        }
    }
}

// ---- histogram: node-level (global atomics) + coarse (LDS-aggregated) ----
__global__ __launch_bounds__(256) void hist2(const int* __restrict__ dst,
                                             int* __restrict__ cnt,
                                             int* __restrict__ ccnt, int E, int NBK) {
    __shared__ int lh[512];
    for (int i = threadIdx.x; i < NBK; i += 256) lh[i] = 0;
    __syncthreads();
    const int base = blockIdx.x * CHUNK;
    #pragma unroll
    for (int i = 0; i < CHUNK / 256; ++i) {
        int e = base + i * 256 + threadIdx.x;
        if (e < E) {
            int d = dst[e];
            atomicAdd(&cnt[d], 1);
            atomicAdd(&lh[d >> BSH], 1);
        }
    }
    __syncthreads();
    for (int i = threadIdx.x; i < NBK; i += 256)
        if (lh[i]) atomicAdd(&ccnt[i], lh[i]);
}

// ---- node-offset scan (N elements, 512/block) ----------------------------
__global__ __launch_bounds__(256) void scan1(const int* __restrict__ cnt, int* __restrict__ off,
                                             int* __restrict__ bsum, int N) {
    __shared__ int sh[256];
    const int t = threadIdx.x;
    const int i0 = blockIdx.x * 512 + t * 2;
    int c0 = (i0 < N) ? cnt[i0] : 0;
    int c1 = (i0 + 1 < N) ? cnt[i0 + 1] : 0;
    int s = c0 + c1;
    sh[t] = s;
    __syncthreads();
    #pragma unroll
    for (int d = 1; d < 256; d <<= 1) {
        int v = (t >= d) ? sh[t - d] : 0;
        __syncthreads();
        sh[t] += v;
        __syncthreads();
    }
    int ex = sh[t] - s;
    if (i0 < N) off[i0] = ex;
    if (i0 + 1 < N) off[i0 + 1] = ex + c0;
    if (t == 255) bsum[blockIdx.x] = sh[255];
}

__global__ __launch_bounds__(256) void scan2(int* __restrict__ bsum, int nB) {
    __shared__ int sh[256];
    const int t = threadIdx.x;
    int v0 = (t < nB) ? bsum[t] : 0;
    sh[t] = v0;
    __syncthreads();
    #pragma unroll
    for (int d = 1; d < 256; d <<= 1) {
        int v = (t >= d) ? sh[t - d] : 0;
        __syncthreads();
        sh[t] += v;
        __syncthreads();
    }
    int ex = sh[t] - v0;
    if (t < nB) bsum[t] = ex;
}

__global__ __launch_bounds__(256) void scan3(int* __restrict__ off, const int* __restrict__ bsum,
                                             int* __restrict__ cursor, int N) {
    int i = blockIdx.x * 256 + threadIdx.x;
    if (i < N) {
        int o = off[i] + bsum[i >> 9];
        off[i] = o;
        cursor[i] = o;
    }
}

// ---- coarse scan: single block, NBK<=512 ---------------------------------
__global__ __launch_bounds__(256) void scanc(const int* __restrict__ ccnt, int* __restrict__ coff,
                                             int* __restrict__ ccur, int NBK) {
    __shared__ int sh[256];
    const int t = threadIdx.x;
    const int i0 = t * 2;
    int c0 = (i0 < NBK) ? ccnt[i0] : 0;
    int c1 = (i0 + 1 < NBK) ? ccnt[i0 + 1] : 0;
    int s = c0 + c1;
    sh[t] = s;
    __syncthreads();
    #pragma unroll
    for (int d = 1; d < 256; d <<= 1) {
        int v = (t >= d) ? sh[t - d] : 0;
        __syncthreads();
        sh[t] += v;
        __syncthreads();
    }
    int ex = sh[t] - s;
    if (i0 < NBK) { coff[i0] = ex; ccur[i0] = ex; }
    if (i0 + 1 < NBK) { coff[i0 + 1] = ex + c0; ccur[i0 + 1] = ex + c0; }
}

// ---- pass 1: coarse bin. LDS rank + one range-reserve atomic per bucket --
// payload: word0 = src(17b) | fp16val15<<17 ; word1 = dst
__global__ __launch_bounds__(256) void binsort1(const float* __restrict__ val,
                                                const int* __restrict__ src,
                                                const int* __restrict__ dst,
                                                int* __restrict__ ccur,
                                                uint2* __restrict__ epk1, int E, int NBK) {
    __shared__ int lh[512];
    __shared__ int lbase[512];
    for (int i = threadIdx.x; i < NBK; i += 256) lh[i] = 0;
    __syncthreads();
    const int base = blockIdx.x * CHUNK;
    int rank[CHUNK / 256];
    int bk[CHUNK / 256];
    #pragma unroll
    for (int i = 0; i < CHUNK / 256; ++i) {
        int e = base + i * 256 + threadIdx.x;
        if (e < E) {
            int b = dst[e] >> BSH;
            bk[i] = b;
            rank[i] = atomicAdd(&lh[b], 1);
        } else bk[i] = -1;
    }
    __syncthreads();
    for (int i = threadIdx.x; i < NBK; i += 256)
        lbase[i] = lh[i] ? atomicAdd(&ccur[i], lh[i]) : 0;
    __syncthreads();
    #pragma unroll
    for (int i = 0; i < CHUNK / 256; ++i) {
        int e = base + i * 256 + threadIdx.x;
        if (e >= E) break;
        int p = lbase[bk[i]] + rank[i];
        __half hv = __float2half(val[e]);
        unsigned short hu;
        __builtin_memcpy(&hu, &hv, 2);
        epk1[p] = make_uint2((unsigned)src[e] | ((unsigned)(hu & 0x7FFFu) << 17),
                             (unsigned)dst[e]);
    }
}

// ---- pass 2: fine bin within bucket (writes confined to ~16KB window) ----
__global__ __launch_bounds__(256) void binsort2(const uint2* __restrict__ epk1,
                                                const int* __restrict__ coff,
                                                const int* __restrict__ ccnt,
                                                int* __restrict__ cursor,
                                                unsigned* __restrict__ epk) {
    const int b = blockIdx.x;
    const int s = coff[b];
    const int n = ccnt[b];
    for (int i = threadIdx.x; i < n; i += 256) {
        uint2 q = epk1[s + i];
        int d = (int)q.y;
        int p = atomicAdd(&cursor[d], 1);
        epk[p] = ((q.x & 0x1FFFFu) << 15) | (q.x >> 17);
    }
}

__device__ __forceinline__ float h15f(unsigned h) {
    unsigned short u = (unsigned short)(h & 0x7FFFu);
    __half hv;
    __builtin_memcpy(&hv, &u, 2);
    return __half2float(hv);
}

// ---- gather: one wave per node; epk broadcast via shfl; bf16 z ------------
__global__ __launch_bounds__(256) void spmm_gather(const unsigned* __restrict__ zz,
                                                   const unsigned* __restrict__ epk,
                                                   const int* __restrict__ off,
                                                   const int* __restrict__ cnt,
                                                   float* __restrict__ out, int N) {
    const int lane = threadIdx.x & 63;
    const int node = (int)((blockIdx.x * (size_t)blockDim.x + threadIdx.x) >> 6);
    if (node >= N) return;
    const int base = off[node];
    const int deg = cnt[node];
    float2 acc = *reinterpret_cast<const float2*>(&out[(size_t)node * 128 + lane * 2]);

    for (int b = 0; b < deg; b += 64) {
        int m = min(64, deg - b);
        unsigned pv = (lane < m) ? epk[base + b + lane] : 0u;
        int j = 0;
        for (; j + 4 <= m; j += 4) {
            unsigned p0 = __shfl(pv, j + 0);
            unsigned p1 = __shfl(pv, j + 1);
            unsigned p2 = __shfl(pv, j + 2);
            unsigned p3 = __shfl(pv, j + 3);
            unsigned z0 = zz[(size_t)(p0 >> 15) * 64 + lane];
            unsigned z1 = zz[(size_t)(p1 >> 15) * 64 + lane];
            unsigned z2 = zz[(size_t)(p2 >> 15) * 64 + lane];
            unsigned z3 = zz[(size_t)(p3 >> 15) * 64 + lane];
            float v0 = h15f(p0), v1 = h15f(p1), v2 = h15f(p2), v3 = h15f(p3);
            acc.x = fmaf(v0, __uint_as_float(z0 << 16), acc.x);
            acc.y = fmaf(v0, __uint_as_float(z0 & 0xFFFF0000u), acc.y);
            acc.x = fmaf(v1, __uint_as_float(z1 << 16), acc.x);
            acc.y = fmaf(v1, __uint_as_float(z1 & 0xFFFF0000u), acc.y);
            acc.x = fmaf(v2, __uint_as_float(z2 << 16), acc.x);
            acc.y = fmaf(v2, __uint_as_float(z2 & 0xFFFF0000u), acc.y);
            acc.x = fmaf(v3, __uint_as_float(z3 << 16), acc.x);
            acc.y = fmaf(v3, __uint_as_float(z3 & 0xFFFF0000u), acc.y);
        }
        for (; j < m; ++j) {
            unsigned p = __shfl(pv, j);
            unsigned zv = zz[(size_t)(p >> 15) * 64 + lane];
            float v = h15f(p);
            acc.x = fmaf(v, __uint_as_float(zv << 16), acc.x);
            acc.y = fmaf(v, __uint_as_float(zv & 0xFFFF0000u), acc.y);
        }
    }
    *reinterpret_cast<float2*>(&out[(size_t)node * 128 + lane * 2]) = acc;
}

extern "C" void kernel_launch(void* const* d_in, const int* in_sizes, int n_in,
                              void* d_out, int out_size, void* d_ws, size_t ws_size,
                              hipStream_t stream) {
    const float* x    = (const float*)d_in[0];
    // d_in[1] = h0 (unused, variant=False)
    const float* aval = (const float*)d_in[2];
    const float* W    = (const float*)d_in[3];
    const float* Wr   = (const float*)d_in[4];
    const int*   asrc = (const int*)d_in[5];
    const int*   adst = (const int*)d_in[6];
    float* out = (float*)d_out;

    const int nx = in_sizes[0];
    const int N = nx / 128;
    const int E = in_sizes[2];
    const int nB = (N + 511) / 512;
    const int NBK = (N + (1 << BSH) - 1) >> BSH;          // 391 coarse buckets
    const int NB1 = (E + CHUNK - 1) / CHUNK;              // 391 edge blocks

    // workspace layout. xb is dead after gemm_mfma -> epk1 aliases it.
    char* w = (char*)d_ws;
    unsigned short* xb = (unsigned short*)w;  w += (size_t)nx * 2;   // 25.6 MB (reused as epk1)
    uint2* epk1 = (uint2*)xb;                                        // 12.8 MB alias
    unsigned short* z  = (unsigned short*)w;  w += (size_t)nx * 2;   // 25.6 MB
    unsigned short* Wt = (unsigned short*)w;  w += 16384 * 2;
    unsigned short* Wrt= (unsigned short*)w;  w += 16384 * 2;
    int* cnt    = (int*)w;  w += (size_t)N * 4;
    int* off    = (int*)w;  w += (size_t)N * 4;
    int* cursor = (int*)w;  w += (size_t)N * 4;
    int* ccnt   = (int*)w;  w += 2048;
    int* coff   = (int*)w;  w += 2048;
    int* ccur   = (int*)w;  w += 2048;
    int* bsum   = (int*)w;  w += 4096;
    unsigned* epk = (unsigned*)w;  w += (size_t)E * 4;               // 6.4 MB

    convert_k<<<(nx / 8 + 255) / 256, 256, 0, stream>>>(x, W, Wr, xb, Wt, Wrt, cnt, ccnt, nx, N, NBK);
    gemm_mfma<<<(N + 127) / 128, 512, 0, stream>>>(xb, Wt, Wrt, z, out, N);
    hist2<<<NB1, 256, 0, stream>>>(adst, cnt, ccnt, E, NBK);
    scan1<<<nB, 256, 0, stream>>>(cnt, off, bsum, N);
    scan2<<<1, 256, 0, stream>>>(bsum, nB);
    scan3<<<(N + 255) / 256, 256, 0, stream>>>(off, bsum, cursor, N);
    scanc<<<1, 256, 0, stream>>>(ccnt, coff, ccur, NBK);
    binsort1<<<NB1, 256, 0, stream>>>(aval, asrc, adst, ccur, epk1, E, NBK);   // epk1 overwrites xb (dead)
    binsort2<<<NBK, 256, 0, stream>>>(epk1, coff, ccnt, cursor, epk);
    spmm_gather<<<(int)(((size_t)N * 64 + 255) / 256), 256, 0, stream>>>((const unsigned*)z, epk, off, cnt, out, N);
}

// Round 6
// 240.482 us; speedup vs baseline: 5.8913x; 1.2439x over previous
//
#include <hip/hip_runtime.h>
#include <hip/hip_fp16.h>

// out = segment_sum(adj_val * x[adj_src], adj_dst) @ W  +  x @ Wr
// z = x@W (bf16 MFMA); out = x@Wr; CSR-by-dst gather on bf16 z.
// GEMM: weights LDS-staged (XOR-swizzled), 32 x-rows/wave, f32->bf16 in-reg.
// CSR via 2-pass bin sort (coarse dst>>8 then fine) to keep random writes
// L2-resident.

typedef __attribute__((ext_vector_type(8))) short bf16x8;
typedef __attribute__((ext_vector_type(4))) float f32x4;

#define BSH 8          // coarse bucket = dst >> 8  (256 nodes per bucket)
#define CHUNK 4096     // edges per block in hist/binsort1

__device__ __forceinline__ unsigned short f2b(float f) {   // f32 -> bf16 RNE
    unsigned u = __float_as_uint(f);
    return (unsigned short)((u + 0x7FFFu + ((u >> 16) & 1u)) >> 16);
}

// ---- prep: Wt/Wrt = bf16(W^T/Wr^T); zero cnt & ccnt ----------------------
__global__ __launch_bounds__(256) void wprep(const float* __restrict__ W,
                                             const float* __restrict__ Wr,
                                             unsigned short* __restrict__ Wt,
                                             unsigned short* __restrict__ Wrt,
                                             int* __restrict__ cnt,
                                             int* __restrict__ ccnt,
                                             int N, int NBK) {
    int gid = blockIdx.x * 256 + threadIdx.x;
    if (gid < 16384) {                 // 128x128 weight transpose
        int k = gid >> 7, n = gid & 127;
        Wt[(n << 7) + k]  = f2b(W[gid]);
        Wrt[(n << 7) + k] = f2b(Wr[gid]);
    }
    if (gid < N) cnt[gid] = 0;
    if (gid < NBK) ccnt[gid] = 0;
}

// ---- MFMA GEMM: weights in LDS (swizzled), 256 rows/block, 8 waves -------
// Swapped operands: A-frag = weight rows (out-cols), B-frag = x rows.
// D layout: col=lane&15 -> x-row, row=(lane>>4)*4+reg -> 4 consecutive cols.
__global__ __launch_bounds__(512) void gemm_mfma(const float* __restrict__ x,
                                                 const unsigned short* __restrict__ Wt,
                                                 const unsigned short* __restrict__ Wrt,
                                                 unsigned short* __restrict__ z,
                                                 float* __restrict__ out, int N) {
    __shared__ uint4 lw[4096];   // [0..2047]=Wt, [2048..4095]=Wrt, 64 KB
    const int tid = threadIdx.x;
    const int wave = tid >> 6;
    const int lane = tid & 63;
    const int l15 = lane & 15;
    const int lhi = lane >> 4;

    // stage weights: chunk c -> row=c>>4, col-chunk swizzled by row&7
    const uint4* wtg = reinterpret_cast<const uint4*>(Wt);
    const uint4* wrg = reinterpret_cast<const uint4*>(Wrt);
    #pragma unroll
    for (int it = 0; it < 4; ++it) {
        int c = it * 512 + tid;
        int row = c >> 4, cc = c & 15;
        int sc = cc ^ (row & 7);
        lw[row * 16 + sc] = wtg[c];
        lw[2048 + row * 16 + sc] = wrg[c];
    }
    __syncthreads();

    const int rowBase = blockIdx.x * 256 + wave * 32;
    const int r0 = rowBase + l15;
    const int r1 = rowBase + 16 + l15;
    const size_t xo0 = (size_t)(r0 < N ? r0 : N - 1) * 128;
    const size_t xo1 = (size_t)(r1 < N ? r1 : N - 1) * 128;

    f32x4 accW[8][2], accR[8][2];
    #pragma unroll
    for (int fn = 0; fn < 8; ++fn) {
        accW[fn][0] = (f32x4)0.f; accW[fn][1] = (f32x4)0.f;
        accR[fn][0] = (f32x4)0.f; accR[fn][1] = (f32x4)0.f;
    }

    #pragma unroll
    for (int ks = 0; ks < 4; ++ks) {
        const int kb = ks * 32 + lhi * 8;
        float4 a0 = *reinterpret_cast<const float4*>(&x[xo0 + kb]);
        float4 b0 = *reinterpret_cast<const float4*>(&x[xo0 + kb + 4]);
        float4 a1 = *reinterpret_cast<const float4*>(&x[xo1 + kb]);
        float4 b1 = *reinterpret_cast<const float4*>(&x[xo1 + kb + 4]);
        union { bf16x8 v; unsigned u[4]; } xf0, xf1;
        xf0.u[0] = (unsigned)f2b(a0.x) | ((unsigned)f2b(a0.y) << 16);
        xf0.u[1] = (unsigned)f2b(a0.z) | ((unsigned)f2b(a0.w) << 16);
        xf0.u[2] = (unsigned)f2b(b0.x) | ((unsigned)f2b(b0.y) << 16);
        xf0.u[3] = (unsigned)f2b(b0.z) | ((unsigned)f2b(b0.w) << 16);
        xf1.u[0] = (unsigned)f2b(a1.x) | ((unsigned)f2b(a1.y) << 16);
        xf1.u[1] = (unsigned)f2b(a1.z) | ((unsigned)f2b(a1.w) << 16);
        xf1.u[2] = (unsigned)f2b(b1.x) | ((unsigned)f2b(b1.y) << 16);
        xf1.u[3] = (unsigned)f2b(b1.z) | ((unsigned)f2b(b1.w) << 16);

        const int sl = ks * 4 + lhi;
        #pragma unroll
        for (int fn = 0; fn < 8; ++fn) {
            int wrow = fn * 16 + l15;
            int idx = wrow * 16 + (sl ^ (wrow & 7));
            bf16x8 wf  = *reinterpret_cast<const bf16x8*>(&lw[idx]);
            bf16x8 wrf = *reinterpret_cast<const bf16x8*>(&lw[2048 + idx]);
            accW[fn][0] = __builtin_amdgcn_mfma_f32_16x16x32_bf16(wf,  xf0.v, accW[fn][0], 0, 0, 0);
            accW[fn][1] = __builtin_amdgcn_mfma_f32_16x16x32_bf16(wf,  xf1.v, accW[fn][1], 0, 0, 0);
            accR[fn][0] = __builtin_amdgcn_mfma_f32_16x16x32_bf16(wrf, xf0.v, accR[fn][0], 0, 0, 0);
            accR[fn][1] = __builtin_amdgcn_mfma_f32_16x16x32_bf16(wrf, xf1.v, accR[fn][1], 0, 0, 0);
        }
    }

    #pragma unroll
    for (int fr = 0; fr < 2; ++fr) {
        int row = rowBase + fr * 16 + l15;
        if (row >= N) continue;
        #pragma unroll
        for (int fn = 0; fn < 8; ++fn) {
            int c = fn * 16 + lhi * 4;
            *reinterpret_cast<f32x4*>(&out[(size_t)row * 128 + c]) = accR[fn][fr];
            uint2 pz;
            pz.x = (unsigned)f2b(accW[fn][fr][0]) | ((unsigned)f2b(accW[fn][fr][1]) << 16);
            pz.y = (unsigned)f2b(accW[fn][fr][2]) | ((unsigned)f2b(accW[fn][fr][3]) << 16);
            *reinterpret_cast<uint2*>(&z[(size_t)row * 128 + c]) = pz;
        }
    }
}

// ---- histogram: node-level (global atomics) + coarse (LDS-aggregated) ----
__global__ __launch_bounds__(256) void hist2(const int* __restrict__ dst,
                                             int* __restrict__ cnt,
                                             int* __restrict__ ccnt, int E, int NBK) {
    __shared__ int lh[512];
    for (int i = threadIdx.x; i < NBK; i += 256) lh[i] = 0;
    __syncthreads();
    const int base = blockIdx.x * CHUNK;
    #pragma unroll
    for (int i = 0; i < CHUNK / 256; ++i) {
        int e = base + i * 256 + threadIdx.x;
        if (e < E) {
            int d = dst[e];
            atomicAdd(&cnt[d], 1);
            atomicAdd(&lh[d >> BSH], 1);
        }
    }
    __syncthreads();
    for (int i = threadIdx.x; i < NBK; i += 256)
        if (lh[i]) atomicAdd(&ccnt[i], lh[i]);
}

// ---- node-offset scan (N elements, 512/block) ----------------------------
__global__ __launch_bounds__(256) void scan1(const int* __restrict__ cnt, int* __restrict__ off,
                                             int* __restrict__ bsum, int N) {
    __shared__ int sh[256];
    const int t = threadIdx.x;
    const int i0 = blockIdx.x * 512 + t * 2;
    int c0 = (i0 < N) ? cnt[i0] : 0;
    int c1 = (i0 + 1 < N) ? cnt[i0 + 1] : 0;
    int s = c0 + c1;
    sh[t] = s;
    __syncthreads();
    #pragma unroll
    for (int d = 1; d < 256; d <<= 1) {
        int v = (t >= d) ? sh[t - d] : 0;
        __syncthreads();
        sh[t] += v;
        __syncthreads();
    }
    int ex = sh[t] - s;
    if (i0 < N) off[i0] = ex;
    if (i0 + 1 < N) off[i0 + 1] = ex + c0;
    if (t == 255) bsum[blockIdx.x] = sh[255];
}

__global__ __launch_bounds__(256) void scan2(int* __restrict__ bsum, int nB) {
    __shared__ int sh[256];
    const int t = threadIdx.x;
    int v0 = (t < nB) ? bsum[t] : 0;
    sh[t] = v0;
    __syncthreads();
    #pragma unroll
    for (int d = 1; d < 256; d <<= 1) {
        int v = (t >= d) ? sh[t - d] : 0;
        __syncthreads();
        sh[t] += v;
        __syncthreads();
    }
    int ex = sh[t] - v0;
    if (t < nB) bsum[t] = ex;
}

__global__ __launch_bounds__(256) void scan3(int* __restrict__ off, const int* __restrict__ bsum,
                                             int* __restrict__ cursor, int N) {
    int i = blockIdx.x * 256 + threadIdx.x;
    if (i < N) {
        int o = off[i] + bsum[i >> 9];
        off[i] = o;
        cursor[i] = o;
    }
}

// ---- coarse scan: single block, NBK<=512 ---------------------------------
__global__ __launch_bounds__(256) void scanc(const int* __restrict__ ccnt, int* __restrict__ coff,
                                             int* __restrict__ ccur, int NBK) {
    __shared__ int sh[256];
    const int t = threadIdx.x;
    const int i0 = t * 2;
    int c0 = (i0 < NBK) ? ccnt[i0] : 0;
    int c1 = (i0 + 1 < NBK) ? ccnt[i0 + 1] : 0;
    int s = c0 + c1;
    sh[t] = s;
    __syncthreads();
    #pragma unroll
    for (int d = 1; d < 256; d <<= 1) {
        int v = (t >= d) ? sh[t - d] : 0;
        __syncthreads();
        sh[t] += v;
        __syncthreads();
    }
    int ex = sh[t] - s;
    if (i0 < NBK) { coff[i0] = ex; ccur[i0] = ex; }
    if (i0 + 1 < NBK) { coff[i0 + 1] = ex + c0; ccur[i0 + 1] = ex + c0; }
}

// ---- pass 1: coarse bin. LDS rank + one range-reserve atomic per bucket --
// payload: word0 = src(17b) | fp16val15<<17 ; word1 = dst
__global__ __launch_bounds__(256) void binsort1(const float* __restrict__ val,
                                                const int* __restrict__ src,
                                                const int* __restrict__ dst,
                                                int* __restrict__ ccur,
                                                uint2* __restrict__ epk1, int E, int NBK) {
    __shared__ int lh[512];
    __shared__ int lbase[512];
    for (int i = threadIdx.x; i < NBK; i += 256) lh[i] = 0;
    __syncthreads();
    const int base = blockIdx.x * CHUNK;
    int rank[CHUNK / 256];
    int bk[CHUNK / 256];
    #pragma unroll
    for (int i = 0; i < CHUNK / 256; ++i) {
        int e = base + i * 256 + threadIdx.x;
        if (e < E) {
            int b = dst[e] >> BSH;
            bk[i] = b;
            rank[i] = atomicAdd(&lh[b], 1);
        } else bk[i] = -1;
    }
    __syncthreads();
    for (int i = threadIdx.x; i < NBK; i += 256)
        lbase[i] = lh[i] ? atomicAdd(&ccur[i], lh[i]) : 0;
    __syncthreads();
    #pragma unroll
    for (int i = 0; i < CHUNK / 256; ++i) {
        int e = base + i * 256 + threadIdx.x;
        if (e >= E) break;
        int p = lbase[bk[i]] + rank[i];
        __half hv = __float2half(val[e]);
        unsigned short hu;
        __builtin_memcpy(&hu, &hv, 2);
        epk1[p] = make_uint2((unsigned)src[e] | ((unsigned)(hu & 0x7FFFu) << 17),
                             (unsigned)dst[e]);
    }
}

// ---- pass 2: fine bin within bucket (writes confined to ~16KB window) ----
__global__ __launch_bounds__(256) void binsort2(const uint2* __restrict__ epk1,
                                                const int* __restrict__ coff,
                                                const int* __restrict__ ccnt,
                                                int* __restrict__ cursor,
                                                unsigned* __restrict__ epk) {
    const int b = blockIdx.x;
    const int s = coff[b];
    const int n = ccnt[b];
    for (int i = threadIdx.x; i < n; i += 256) {
        uint2 q = epk1[s + i];
        int d = (int)q.y;
        int p = atomicAdd(&cursor[d], 1);
        epk[p] = ((q.x & 0x1FFFFu) << 15) | (q.x >> 17);
    }
}

__device__ __forceinline__ float h15f(unsigned h) {
    unsigned short u = (unsigned short)(h & 0x7FFFu);
    __half hv;
    __builtin_memcpy(&hv, &u, 2);
    return __half2float(hv);
}

// ---- gather: one wave per node; epk broadcast via shfl; bf16 z ------------
__global__ __launch_bounds__(256) void spmm_gather(const unsigned* __restrict__ zz,
                                                   const unsigned* __restrict__ epk,
                                                   const int* __restrict__ off,
                                                   const int* __restrict__ cnt,
                                                   float* __restrict__ out, int N) {
    const int lane = threadIdx.x & 63;
    const int node = (int)((blockIdx.x * (size_t)blockDim.x + threadIdx.x) >> 6);
    if (node >= N) return;
    const int base = off[node];
    const int deg = cnt[node];
    float2 acc = *reinterpret_cast<const float2*>(&out[(size_t)node * 128 + lane * 2]);

    for (int b = 0; b < deg; b += 64) {
        int m = min(64, deg - b);
        unsigned pv = (lane < m) ? epk[base + b + lane] : 0u;
        int j = 0;
        for (; j + 4 <= m; j += 4) {
            unsigned p0 = __shfl(pv, j + 0);
            unsigned p1 = __shfl(pv, j + 1);
            unsigned p2 = __shfl(pv, j + 2);
            unsigned p3 = __shfl(pv, j + 3);
            unsigned z0 = zz[(size_t)(p0 >> 15) * 64 + lane];
            unsigned z1 = zz[(size_t)(p1 >> 15) * 64 + lane];
            unsigned z2 = zz[(size_t)(p2 >> 15) * 64 + lane];
            unsigned z3 = zz[(size_t)(p3 >> 15) * 64 + lane];
            float v0 = h15f(p0), v1 = h15f(p1), v2 = h15f(p2), v3 = h15f(p3);
            acc.x = fmaf(v0, __uint_as_float(z0 << 16), acc.x);
            acc.y = fmaf(v0, __uint_as_float(z0 & 0xFFFF0000u), acc.y);
            acc.x = fmaf(v1, __uint_as_float(z1 << 16), acc.x);
            acc.y = fmaf(v1, __uint_as_float(z1 & 0xFFFF0000u), acc.y);
            acc.x = fmaf(v2, __uint_as_float(z2 << 16), acc.x);
            acc.y = fmaf(v2, __uint_as_float(z2 & 0xFFFF0000u), acc.y);
            acc.x = fmaf(v3, __uint_as_float(z3 << 16), acc.x);
            acc.y = fmaf(v3, __uint_as_float(z3 & 0xFFFF0000u), acc.y);
        }
        for (; j < m; ++j) {
            unsigned p = __shfl(pv, j);
            unsigned zv = zz[(size_t)(p >> 15) * 64 + lane];
            float v = h15f(p);
            acc.x = fmaf(v, __uint_as_float(zv << 16), acc.x);
            acc.y = fmaf(v, __uint_as_float(zv & 0xFFFF0000u), acc.y);
        }
    }
    *reinterpret_cast<float2*>(&out[(size_t)node * 128 + lane * 2]) = acc;
}

extern "C" void kernel_launch(void* const* d_in, const int* in_sizes, int n_in,
                              void* d_out, int out_size, void* d_ws, size_t ws_size,
                              hipStream_t stream) {
    const float* x    = (const float*)d_in[0];
    // d_in[1] = h0 (unused, variant=False)
    const float* aval = (const float*)d_in[2];
    const float* W    = (const float*)d_in[3];
    const float* Wr   = (const float*)d_in[4];
    const int*   asrc = (const int*)d_in[5];
    const int*   adst = (const int*)d_in[6];
    float* out = (float*)d_out;

    const int nx = in_sizes[0];
    const int N = nx / 128;
    const int E = in_sizes[2];
    const int nB = (N + 511) / 512;
    const int NBK = (N + (1 << BSH) - 1) >> BSH;          // 391 coarse buckets
    const int NB1 = (E + CHUNK - 1) / CHUNK;              // 391 edge blocks

    // workspace layout
    char* w = (char*)d_ws;
    uint2* epk1 = (uint2*)w;                  w += (size_t)E * 8;    // 12.8 MB
    unsigned short* z  = (unsigned short*)w;  w += (size_t)nx * 2;   // 25.6 MB
    unsigned short* Wt = (unsigned short*)w;  w += 16384 * 2;
    unsigned short* Wrt= (unsigned short*)w;  w += 16384 * 2;
    int* cnt    = (int*)w;  w += (size_t)N * 4;
    int* off    = (int*)w;  w += (size_t)N * 4;
    int* cursor = (int*)w;  w += (size_t)N * 4;
    int* ccnt   = (int*)w;  w += 2048;
    int* coff   = (int*)w;  w += 2048;
    int* ccur   = (int*)w;  w += 2048;
    int* bsum   = (int*)w;  w += 4096;
    unsigned* epk = (unsigned*)w;  w += (size_t)E * 4;               // 6.4 MB

    wprep<<<(N + 255) / 256, 256, 0, stream>>>(W, Wr, Wt, Wrt, cnt, ccnt, N, NBK);
    gemm_mfma<<<(N + 255) / 256, 512, 0, stream>>>(x, Wt, Wrt, z, out, N);
    hist2<<<NB1, 256, 0, stream>>>(adst, cnt, ccnt, E, NBK);
    scan1<<<nB, 256, 0, stream>>>(cnt, off, bsum, N);
    scan2<<<1, 256, 0, stream>>>(bsum, nB);
    scan3<<<(N + 255) / 256, 256, 0, stream>>>(off, bsum, cursor, N);
    scanc<<<1, 256, 0, stream>>>(ccnt, coff, ccur, NBK);
    binsort1<<<NB1, 256, 0, stream>>>(aval, asrc, adst, ccur, epk1, E, NBK);
    binsort2<<<NBK, 256, 0, stream>>>(epk1, coff, ccnt, cursor, epk);
    spmm_gather<<<(int)(((size_t)N * 64 + 255) / 256), 256, 0, stream>>>((const unsigned*)z, epk, off, cnt, out, N);
}

// Round 7
// 159.466 us; speedup vs baseline: 8.8844x; 1.5080x over previous
//
#include <hip/hip_runtime.h>
#include <hip/hip_fp16.h>

// out = segment_sum(adj_val * x[adj_src], adj_dst) @ W  +  x @ Wr
// z = x@W (bf16 MFMA); out = x@Wr; CSR-by-dst gather on bf16 z.
// CSR: coarse histogram (LDS-aggregated) -> coarse bin -> fused fine sort
// that builds per-node counts/offsets in LDS per bucket (no global per-node
// atomics: r6 showed they cost 72us/50MB of L2 line thrash).

typedef __attribute__((ext_vector_type(8))) short bf16x8;
typedef __attribute__((ext_vector_type(4))) float f32x4;

#define BSH 8          // coarse bucket = dst >> 8  (256 nodes per bucket)
#define CHUNK 4096     // edges per block in histc/binsort1

__device__ __forceinline__ unsigned short f2b(float f) {   // f32 -> bf16 RNE
    unsigned u = __float_as_uint(f);
    return (unsigned short)((u + 0x7FFFu + ((u >> 16) & 1u)) >> 16);
}

// ---- prep: Wt/Wrt = bf16(W^T/Wr^T); zero ccnt ----------------------------
__global__ __launch_bounds__(256) void wprep(const float* __restrict__ W,
                                             const float* __restrict__ Wr,
                                             unsigned short* __restrict__ Wt,
                                             unsigned short* __restrict__ Wrt,
                                             int* __restrict__ ccnt,
                                             int NBK) {
    int gid = blockIdx.x * 256 + threadIdx.x;
    if (gid < 16384) {                 // 128x128 weight transpose
        int k = gid >> 7, n = gid & 127;
        Wt[(n << 7) + k]  = f2b(W[gid]);
        Wrt[(n << 7) + k] = f2b(Wr[gid]);
    }
    if (gid < NBK) ccnt[gid] = 0;
}

// ---- MFMA GEMM: weights in LDS (swizzled), 256 rows/block, 8 waves -------
__global__ __launch_bounds__(512) void gemm_mfma(const float* __restrict__ x,
                                                 const unsigned short* __restrict__ Wt,
                                                 const unsigned short* __restrict__ Wrt,
                                                 unsigned short* __restrict__ z,
                                                 float* __restrict__ out, int N) {
    __shared__ uint4 lw[4096];   // [0..2047]=Wt, [2048..4095]=Wrt, 64 KB
    const int tid = threadIdx.x;
    const int wave = tid >> 6;
    const int lane = tid & 63;
    const int l15 = lane & 15;
    const int lhi = lane >> 4;

    const uint4* wtg = reinterpret_cast<const uint4*>(Wt);
    const uint4* wrg = reinterpret_cast<const uint4*>(Wrt);
    #pragma unroll
    for (int it = 0; it < 4; ++it) {
        int c = it * 512 + tid;
        int row = c >> 4, cc = c & 15;
        int sc = cc ^ (row & 7);
        lw[row * 16 + sc] = wtg[c];
        lw[2048 + row * 16 + sc] = wrg[c];
    }
    __syncthreads();

    const int rowBase = blockIdx.x * 256 + wave * 32;
    const int r0 = rowBase + l15;
    const int r1 = rowBase + 16 + l15;
    const size_t xo0 = (size_t)(r0 < N ? r0 : N - 1) * 128;
    const size_t xo1 = (size_t)(r1 < N ? r1 : N - 1) * 128;

    f32x4 accW[8][2], accR[8][2];
    #pragma unroll
    for (int fn = 0; fn < 8; ++fn) {
        accW[fn][0] = (f32x4)0.f; accW[fn][1] = (f32x4)0.f;
        accR[fn][0] = (f32x4)0.f; accR[fn][1] = (f32x4)0.f;
    }

    #pragma unroll
    for (int ks = 0; ks < 4; ++ks) {
        const int kb = ks * 32 + lhi * 8;
        float4 a0 = *reinterpret_cast<const float4*>(&x[xo0 + kb]);
        float4 b0 = *reinterpret_cast<const float4*>(&x[xo0 + kb + 4]);
        float4 a1 = *reinterpret_cast<const float4*>(&x[xo1 + kb]);
        float4 b1 = *reinterpret_cast<const float4*>(&x[xo1 + kb + 4]);
        union { bf16x8 v; unsigned u[4]; } xf0, xf1;
        xf0.u[0] = (unsigned)f2b(a0.x) | ((unsigned)f2b(a0.y) << 16);
        xf0.u[1] = (unsigned)f2b(a0.z) | ((unsigned)f2b(a0.w) << 16);
        xf0.u[2] = (unsigned)f2b(b0.x) | ((unsigned)f2b(b0.y) << 16);
        xf0.u[3] = (unsigned)f2b(b0.z) | ((unsigned)f2b(b0.w) << 16);
        xf1.u[0] = (unsigned)f2b(a1.x) | ((unsigned)f2b(a1.y) << 16);
        xf1.u[1] = (unsigned)f2b(a1.z) | ((unsigned)f2b(a1.w) << 16);
        xf1.u[2] = (unsigned)f2b(b1.x) | ((unsigned)f2b(b1.y) << 16);
        xf1.u[3] = (unsigned)f2b(b1.z) | ((unsigned)f2b(b1.w) << 16);

        const int sl = ks * 4 + lhi;
        #pragma unroll
        for (int fn = 0; fn < 8; ++fn) {
            int wrow = fn * 16 + l15;
            int idx = wrow * 16 + (sl ^ (wrow & 7));
            bf16x8 wf  = *reinterpret_cast<const bf16x8*>(&lw[idx]);
            bf16x8 wrf = *reinterpret_cast<const bf16x8*>(&lw[2048 + idx]);
            accW[fn][0] = __builtin_amdgcn_mfma_f32_16x16x32_bf16(wf,  xf0.v, accW[fn][0], 0, 0, 0);
            accW[fn][1] = __builtin_amdgcn_mfma_f32_16x16x32_bf16(wf,  xf1.v, accW[fn][1], 0, 0, 0);
            accR[fn][0] = __builtin_amdgcn_mfma_f32_16x16x32_bf16(wrf, xf0.v, accR[fn][0], 0, 0, 0);
            accR[fn][1] = __builtin_amdgcn_mfma_f32_16x16x32_bf16(wrf, xf1.v, accR[fn][1], 0, 0, 0);
        }
    }

    #pragma unroll
    for (int fr = 0; fr < 2; ++fr) {
        int row = rowBase + fr * 16 + l15;
        if (row >= N) continue;
        #pragma unroll
        for (int fn = 0; fn < 8; ++fn) {
            int c = fn * 16 + lhi * 4;
            *reinterpret_cast<f32x4*>(&out[(size_t)row * 128 + c]) = accR[fn][fr];
            uint2 pz;
            pz.x = (unsigned)f2b(accW[fn][fr][0]) | ((unsigned)f2b(accW[fn][fr][1]) << 16);
            pz.y = (unsigned)f2b(accW[fn][fr][2]) | ((unsigned)f2b(accW[fn][fr][3]) << 16);
            *reinterpret_cast<uint2*>(&z[(size_t)row * 128 + c]) = pz;
        }
    }
}

// ---- coarse histogram only (LDS-aggregated) ------------------------------
__global__ __launch_bounds__(256) void histc(const int* __restrict__ dst,
                                             int* __restrict__ ccnt, int E, int NBK) {
    __shared__ int lh[512];
    for (int i = threadIdx.x; i < NBK; i += 256) lh[i] = 0;
    __syncthreads();
    const int base = blockIdx.x * CHUNK;
    #pragma unroll
    for (int i = 0; i < CHUNK / 256; ++i) {
        int e = base + i * 256 + threadIdx.x;
        if (e < E) atomicAdd(&lh[dst[e] >> BSH], 1);
    }
    __syncthreads();
    for (int i = threadIdx.x; i < NBK; i += 256)
        if (lh[i]) atomicAdd(&ccnt[i], lh[i]);
}

// ---- coarse scan: single block, NBK<=512 ---------------------------------
__global__ __launch_bounds__(256) void scanc(const int* __restrict__ ccnt, int* __restrict__ coff,
                                             int* __restrict__ ccur, int NBK) {
    __shared__ int sh[256];
    const int t = threadIdx.x;
    const int i0 = t * 2;
    int c0 = (i0 < NBK) ? ccnt[i0] : 0;
    int c1 = (i0 + 1 < NBK) ? ccnt[i0 + 1] : 0;
    int s = c0 + c1;
    sh[t] = s;
    __syncthreads();
    #pragma unroll
    for (int d = 1; d < 256; d <<= 1) {
        int v = (t >= d) ? sh[t - d] : 0;
        __syncthreads();
        sh[t] += v;
        __syncthreads();
    }
    int ex = sh[t] - s;
    if (i0 < NBK) { coff[i0] = ex; ccur[i0] = ex; }
    if (i0 + 1 < NBK) { coff[i0 + 1] = ex + c0; ccur[i0 + 1] = ex + c0; }
}

// ---- pass 1: coarse bin. LDS rank + one range-reserve atomic per bucket --
// payload: word0 = src(17b) | fp16val15<<17 ; word1 = dst
__global__ __launch_bounds__(256) void binsort1(const float* __restrict__ val,
                                                const int* __restrict__ src,
                                                const int* __restrict__ dst,
                                                int* __restrict__ ccur,
                                                uint2* __restrict__ epk1, int E, int NBK) {
    __shared__ int lh[512];
    __shared__ int lbase[512];
    for (int i = threadIdx.x; i < NBK; i += 256) lh[i] = 0;
    __syncthreads();
    const int base = blockIdx.x * CHUNK;
    int rank[CHUNK / 256];
    int bk[CHUNK / 256];
    #pragma unroll
    for (int i = 0; i < CHUNK / 256; ++i) {
        int e = base + i * 256 + threadIdx.x;
        if (e < E) {
            int b = dst[e] >> BSH;
            bk[i] = b;
            rank[i] = atomicAdd(&lh[b], 1);
        } else bk[i] = -1;
    }
    __syncthreads();
    for (int i = threadIdx.x; i < NBK; i += 256)
        lbase[i] = lh[i] ? atomicAdd(&ccur[i], lh[i]) : 0;
    __syncthreads();
    #pragma unroll
    for (int i = 0; i < CHUNK / 256; ++i) {
        int e = base + i * 256 + threadIdx.x;
        if (e >= E) break;
        int p = lbase[bk[i]] + rank[i];
        __half hv = __float2half(val[e]);
        unsigned short hu;
        __builtin_memcpy(&hu, &hv, 2);
        epk1[p] = make_uint2((unsigned)src[e] | ((unsigned)(hu & 0x7FFFu) << 17),
                             (unsigned)dst[e]);
    }
}

// ---- pass 2: fine sort within bucket + per-node off/cnt (all in LDS) -----
// One block per coarse bucket (256 nodes, ~4K edges). No global atomics.
__global__ __launch_bounds__(256) void binsort2(const uint2* __restrict__ epk1,
                                                const int* __restrict__ coff,
                                                const int* __restrict__ ccnt,
                                                unsigned* __restrict__ epk,
                                                int* __restrict__ off,
                                                int* __restrict__ cnt, int N) {
    __shared__ int lcnt[256];
    __shared__ int sh[256];
    __shared__ int lcur[256];
    const int b = blockIdx.x;
    const int s = coff[b];
    const int n = ccnt[b];
    const int t = threadIdx.x;
    const int gnode = (b << BSH) + t;

    lcnt[t] = 0;
    __syncthreads();
    for (int i = t; i < n; i += 256)
        atomicAdd(&lcnt[epk1[s + i].y & 255], 1);
    __syncthreads();

    int c = lcnt[t];
    sh[t] = c;
    __syncthreads();
    #pragma unroll
    for (int d = 1; d < 256; d <<= 1) {
        int v = (t >= d) ? sh[t - d] : 0;
        __syncthreads();
        sh[t] += v;
        __syncthreads();
    }
    int ex = sh[t] - c;
    lcur[t] = ex;
    if (gnode < N) {
        off[gnode] = s + ex;
        cnt[gnode] = c;
    }
    __syncthreads();

    for (int i = t; i < n; i += 256) {
        uint2 q = epk1[s + i];
        int p = s + atomicAdd(&lcur[q.y & 255], 1);
        epk[p] = ((q.x & 0x1FFFFu) << 15) | (q.x >> 17);
    }
}

__device__ __forceinline__ float h15f(unsigned h) {
    unsigned short u = (unsigned short)(h & 0x7FFFu);
    __half hv;
    __builtin_memcpy(&hv, &u, 2);
    return __half2float(hv);
}

// ---- gather: one wave per node; epk broadcast via shfl; bf16 z ------------
__global__ __launch_bounds__(256) void spmm_gather(const unsigned* __restrict__ zz,
                                                   const unsigned* __restrict__ epk,
                                                   const int* __restrict__ off,
                                                   const int* __restrict__ cnt,
                                                   float* __restrict__ out, int N) {
    const int lane = threadIdx.x & 63;
    const int node = (int)((blockIdx.x * (size_t)blockDim.x + threadIdx.x) >> 6);
    if (node >= N) return;
    const int base = off[node];
    const int deg = cnt[node];
    float2 acc = *reinterpret_cast<const float2*>(&out[(size_t)node * 128 + lane * 2]);

    for (int b = 0; b < deg; b += 64) {
        int m = min(64, deg - b);
        unsigned pv = (lane < m) ? epk[base + b + lane] : 0u;
        int j = 0;
        for (; j + 4 <= m; j += 4) {
            unsigned p0 = __shfl(pv, j + 0);
            unsigned p1 = __shfl(pv, j + 1);
            unsigned p2 = __shfl(pv, j + 2);
            unsigned p3 = __shfl(pv, j + 3);
            unsigned z0 = zz[(size_t)(p0 >> 15) * 64 + lane];
            unsigned z1 = zz[(size_t)(p1 >> 15) * 64 + lane];
            unsigned z2 = zz[(size_t)(p2 >> 15) * 64 + lane];
            unsigned z3 = zz[(size_t)(p3 >> 15) * 64 + lane];
            float v0 = h15f(p0), v1 = h15f(p1), v2 = h15f(p2), v3 = h15f(p3);
            acc.x = fmaf(v0, __uint_as_float(z0 << 16), acc.x);
            acc.y = fmaf(v0, __uint_as_float(z0 & 0xFFFF0000u), acc.y);
            acc.x = fmaf(v1, __uint_as_float(z1 << 16), acc.x);
            acc.y = fmaf(v1, __uint_as_float(z1 & 0xFFFF0000u), acc.y);
            acc.x = fmaf(v2, __uint_as_float(z2 << 16), acc.x);
            acc.y = fmaf(v2, __uint_as_float(z2 & 0xFFFF0000u), acc.y);
            acc.x = fmaf(v3, __uint_as_float(z3 << 16), acc.x);
            acc.y = fmaf(v3, __uint_as_float(z3 & 0xFFFF0000u), acc.y);
        }
        for (; j < m; ++j) {
            unsigned p = __shfl(pv, j);
            unsigned zv = zz[(size_t)(p >> 15) * 64 + lane];
            float v = h15f(p);
            acc.x = fmaf(v, __uint_as_float(zv << 16), acc.x);
            acc.y = fmaf(v, __uint_as_float(zv & 0xFFFF0000u), acc.y);
        }
    }
    *reinterpret_cast<float2*>(&out[(size_t)node * 128 + lane * 2]) = acc;
}

extern "C" void kernel_launch(void* const* d_in, const int* in_sizes, int n_in,
                              void* d_out, int out_size, void* d_ws, size_t ws_size,
                              hipStream_t stream) {
    const float* x    = (const float*)d_in[0];
    // d_in[1] = h0 (unused, variant=False)
    const float* aval = (const float*)d_in[2];
    const float* W    = (const float*)d_in[3];
    const float* Wr   = (const float*)d_in[4];
    const int*   asrc = (const int*)d_in[5];
    const int*   adst = (const int*)d_in[6];
    float* out = (float*)d_out;

    const int nx = in_sizes[0];
    const int N = nx / 128;
    const int E = in_sizes[2];
    const int NBK = (N + (1 << BSH) - 1) >> BSH;          // 391 coarse buckets
    const int NB1 = (E + CHUNK - 1) / CHUNK;              // 391 edge blocks

    // workspace layout
    char* w = (char*)d_ws;
    uint2* epk1 = (uint2*)w;                  w += (size_t)E * 8;    // 12.8 MB
    unsigned short* z  = (unsigned short*)w;  w += (size_t)nx * 2;   // 25.6 MB
    unsigned short* Wt = (unsigned short*)w;  w += 16384 * 2;
    unsigned short* Wrt= (unsigned short*)w;  w += 16384 * 2;
    int* off    = (int*)w;  w += (size_t)N * 4;
    int* cnt    = (int*)w;  w += (size_t)N * 4;
    int* ccnt   = (int*)w;  w += 2048;
    int* coff   = (int*)w;  w += 2048;
    int* ccur   = (int*)w;  w += 2048;
    unsigned* epk = (unsigned*)w;  w += (size_t)E * 4;               // 6.4 MB

    wprep<<<(16384 + 255) / 256, 256, 0, stream>>>(W, Wr, Wt, Wrt, ccnt, NBK);
    gemm_mfma<<<(N + 255) / 256, 512, 0, stream>>>(x, Wt, Wrt, z, out, N);
    histc<<<NB1, 256, 0, stream>>>(adst, ccnt, E, NBK);
    scanc<<<1, 256, 0, stream>>>(ccnt, coff, ccur, NBK);
    binsort1<<<NB1, 256, 0, stream>>>(aval, asrc, adst, ccur, epk1, E, NBK);
    binsort2<<<NBK, 256, 0, stream>>>(epk1, coff, ccnt, epk, off, cnt, N);
    spmm_gather<<<(int)(((size_t)N * 64 + 255) / 256), 256, 0, stream>>>((const unsigned*)z, epk, off, cnt, out, N);
}